// Round 2
// baseline (114.185 us; speedup 1.0000x reference)
//
#include <hip/hip_runtime.h>

#define D        4096
#define NERR     8192
#define D4       (D / 4)            // 1024 float4 per row

// ---------------- Kernel A: partial column sums of |e| ----------------
// grid = ROWCH * 4 blocks, 256 threads. Each block: RPC rows x 1024 cols.
template<int RPC>
__global__ void k_colsum_partial(const float4* __restrict__ e4,
                                 float4* __restrict__ part4) {
    const int t     = threadIdx.x;
    const int cb    = blockIdx.x & 3;     // 4 column blocks of 1024 f4-cols
    const int chunk = blockIdx.x >> 2;    // row chunk
    const int col4  = cb * 256 + t;       // float4 column index [0,1024)
    const float4* p = e4 + (size_t)chunk * RPC * D4 + col4;

    float4 acc = make_float4(0.f, 0.f, 0.f, 0.f);
    #pragma unroll 8
    for (int r = 0; r < RPC; ++r) {
        float4 v = p[(size_t)r * D4];
        acc.x += fabsf(v.x);
        acc.y += fabsf(v.y);
        acc.z += fabsf(v.z);
        acc.w += fabsf(v.w);
    }
    part4[chunk * D4 + col4] = acc;
}

// ---------------- Kernel B: reduce partials + per-column transform -----
// grid = D/256 = 16 blocks, 256 threads; one thread per column.
__global__ void k_finalize_cols(const float* __restrict__ part,
                                const float* __restrict__ center,
                                float* __restrict__ out_center,
                                float* __restrict__ col_scale,
                                float* __restrict__ mu_arr,
                                int rowch) {
    const int col = blockIdx.x * 256 + threadIdx.x;
    float apt = 0.f;
    #pragma unroll 8
    for (int k = 0; k < rowch; ++k) apt += part[k * D + col];

    const float c  = center[col];
    const float ub = c + apt;
    const float lb = c - apt;
    const bool cross = (ub > 0.f) && (lb < 0.f);
    const bool act   = (lb >= 0.f);

    const float denom = cross ? (ub - lb) : 1.f;
    const float slope = cross ? (ub / denom) : 0.f;
    const float mu    = cross ? (-slope * lb * 0.5f) : 0.f;

    out_center[col] = act ? c : (slope * c + mu);
    col_scale[col]  = act ? 1.f : slope;
    mu_arr[col]     = mu;
}

// ---------------- Kernel CD: top = e * col_scale  AND  bottom = diag(mu)
// One grid-stride loop over 12M float4 (8M top + 4M bottom).
__global__ void k_write_top_bottom(const float4* __restrict__ e4,
                                   const float4* __restrict__ cs4,
                                   const float*  __restrict__ mu_arr,
                                   float4* __restrict__ top4,
                                   float4* __restrict__ bot4) {
    const int TOP4   = NERR * D4;          // 8,388,608
    const int N4     = TOP4 + D * D4;      // 12,582,912
    const int stride = gridDim.x * blockDim.x;
    for (int i = blockIdx.x * blockDim.x + threadIdx.x; i < N4; i += stride) {
        if (i < TOP4) {
            const int c4 = i & (D4 - 1);
            float4 v = e4[i];
            const float4 s = cs4[c4];
            v.x *= s.x; v.y *= s.y; v.z *= s.z; v.w *= s.w;
            top4[i] = v;
        } else {
            const int j   = i - TOP4;
            const int row = j >> 10;           // / D4
            const int j4  = j & (D4 - 1);
            float4 v = make_float4(0.f, 0.f, 0.f, 0.f);
            if (j4 == (row >> 2)) {
                const float m = mu_arr[row];
                ((float*)&v)[row & 3] = m;
            }
            bot4[j] = v;
        }
    }
}

extern "C" void kernel_launch(void* const* d_in, const int* in_sizes, int n_in,
                              void* d_out, int out_size, void* d_ws, size_t ws_size,
                              hipStream_t stream) {
    const float* center = (const float*)d_in[0];   // (4096,)
    const float* error  = (const float*)d_in[1];   // (8192, 4096)
    float* out = (float*)d_out;
    float* ws  = (float*)d_ws;

    // Pick row-chunk count by available workspace (deterministic in ws_size).
    const size_t need256 = ((size_t)256 * D + 2 * D) * sizeof(float);  // ~4.2 MB
    const int rowch = (ws_size >= need256) ? 256 : 64;

    // ws layout (floats): [partials: rowch*D][col_scale: D][mu: D]
    float* part      = ws;
    float* col_scale = ws + (size_t)rowch * D;
    float* mu_arr    = col_scale + D;

    float* out_center = out;                                   // (4096,)
    float* out_top    = out + D;                               // (8192, 4096)
    float* out_bottom = out + (size_t)D + (size_t)NERR * D;    // (4096, 4096)

    if (rowch == 256) {
        k_colsum_partial<NERR / 256><<<256 * 4, 256, 0, stream>>>(
            (const float4*)error, (float4*)part);
    } else {
        k_colsum_partial<NERR / 64><<<64 * 4, 256, 0, stream>>>(
            (const float4*)error, (float4*)part);
    }
    k_finalize_cols<<<D / 256, 256, 0, stream>>>(
        part, center, out_center, col_scale, mu_arr, rowch);
    k_write_top_bottom<<<2048, 256, 0, stream>>>(
        (const float4*)error, (const float4*)col_scale, mu_arr,
        (float4*)out_top, (float4*)out_bottom);
}

// Round 4
// 87.700 us; speedup vs baseline: 1.3020x; 1.3020x over previous
//
#include <hip/hip_runtime.h>

#define D        4096
#define NERR     8192
#define ROWCH    64                 // row chunks for partial column sums
#define RPC      (NERR / ROWCH)     // 128 rows per chunk
#define D4       (D / 4)            // 1024 float4 per row

typedef float f32x4 __attribute__((ext_vector_type(4)));  // NT-builtin-compatible

// ---------------- Kernel A: partial column sums of |e| ----------------
// grid = ROWCH * 4 = 256 blocks, 256 threads. Each block: 128 rows x 1024 f4-cols.
__global__ void k_colsum_partial(const f32x4* __restrict__ e4,
                                 f32x4* __restrict__ part4) {
    const int t     = threadIdx.x;
    const int cb    = blockIdx.x & 3;     // 4 column blocks of 1024 f4-cols
    const int chunk = blockIdx.x >> 2;    // 64 row chunks
    const int col4  = cb * 256 + t;       // float4 column index [0,1024)
    const f32x4* p = e4 + (size_t)chunk * RPC * D4 + col4;

    f32x4 acc = (f32x4)(0.f, 0.f, 0.f, 0.f);
    #pragma unroll 8
    for (int r = 0; r < RPC; ++r) {
        f32x4 v = p[(size_t)r * D4];
        acc.x += fabsf(v.x);
        acc.y += fabsf(v.y);
        acc.z += fabsf(v.z);
        acc.w += fabsf(v.w);
    }
    part4[chunk * D4 + col4] = acc;
}

// ---------------- Kernel B: reduce partials + per-column transform -----
// grid = D/256 = 16 blocks, 256 threads; one thread per column. 1 MB read.
__global__ void k_finalize_cols(const float* __restrict__ part,
                                const float* __restrict__ center,
                                float* __restrict__ out_center,
                                float* __restrict__ col_scale,
                                float* __restrict__ mu_arr) {
    const int col = blockIdx.x * 256 + threadIdx.x;
    float apt = 0.f;
    #pragma unroll 8
    for (int k = 0; k < ROWCH; ++k) apt += part[k * D + col];

    const float c  = center[col];
    const float ub = c + apt;
    const float lb = c - apt;
    const bool cross = (ub > 0.f) && (lb < 0.f);
    const bool act   = (lb >= 0.f);

    const float denom = cross ? (ub - lb) : 1.f;
    const float slope = cross ? (ub / denom) : 0.f;
    const float mu    = cross ? (-slope * lb * 0.5f) : 0.f;

    out_center[col] = act ? c : (slope * c + mu);
    col_scale[col]  = act ? 1.f : slope;
    mu_arr[col]     = mu;
}

// ---------------- Kernel C: top = e * col_scale ------------------------
// grid-stride; stride (2048*256) is a multiple of D4 so each thread's
// column is loop-invariant -> hoist the scale load. NT load (last use of e)
// + NT store (streaming output).
__global__ void k_scale_top(const f32x4* __restrict__ e4,
                            const f32x4* __restrict__ cs4,
                            f32x4* __restrict__ out4) {
    const int n4     = NERR * D4;                 // 8,388,608
    const int stride = gridDim.x * blockDim.x;    // 524,288 = 512*D4
    const int tid    = blockIdx.x * blockDim.x + threadIdx.x;
    const f32x4 s    = cs4[tid & (D4 - 1)];
    for (int i = tid; i < n4; i += stride) {
        f32x4 v = __builtin_nontemporal_load(&e4[i]);
        v *= s;
        __builtin_nontemporal_store(v, &out4[i]);
    }
}

// ---------------- Kernel D: bottom = diag(mu) --------------------------
// grid-stride; zeros except one diag element per row. NT stores.
__global__ void k_write_bottom(const float* __restrict__ mu_arr,
                               f32x4* __restrict__ out4) {
    const int n4     = D * D4;                    // 4,194,304
    const int stride = gridDim.x * blockDim.x;
    const int tid    = blockIdx.x * blockDim.x + threadIdx.x;
    const int j4     = tid & (D4 - 1);            // loop-invariant f4-col
    for (int i = tid; i < n4; i += stride) {
        const int row = i >> 10;                  // / D4
        f32x4 v = (f32x4)(0.f, 0.f, 0.f, 0.f);
        if (j4 == (row >> 2)) {
            v[row & 3] = mu_arr[row];
        }
        __builtin_nontemporal_store(v, &out4[i]);
    }
}

extern "C" void kernel_launch(void* const* d_in, const int* in_sizes, int n_in,
                              void* d_out, int out_size, void* d_ws, size_t ws_size,
                              hipStream_t stream) {
    const float* center = (const float*)d_in[0];   // (4096,)
    const float* error  = (const float*)d_in[1];   // (8192, 4096)
    float* out = (float*)d_out;
    float* ws  = (float*)d_ws;

    // ws layout (floats): [partials: ROWCH*D = 1 MB][col_scale: D][mu: D]
    float* part      = ws;
    float* col_scale = ws + (size_t)ROWCH * D;
    float* mu_arr    = col_scale + D;

    float* out_center = out;                                   // (4096,)
    float* out_top    = out + D;                               // (8192, 4096)
    float* out_bottom = out + (size_t)D + (size_t)NERR * D;    // (4096, 4096)

    k_colsum_partial<<<ROWCH * 4, 256, 0, stream>>>(
        (const f32x4*)error, (f32x4*)part);
    k_finalize_cols<<<D / 256, 256, 0, stream>>>(
        part, center, out_center, col_scale, mu_arr);
    k_scale_top<<<2048, 256, 0, stream>>>(
        (const f32x4*)error, (const f32x4*)col_scale, (f32x4*)out_top);
    k_write_bottom<<<2048, 256, 0, stream>>>(
        mu_arr, (f32x4*)out_bottom);
}